// Round 13
// baseline (612.482 us; speedup 1.0000x reference)
//
#include <hip/hip_runtime.h>

// ---------------- problem constants ----------------
#define BB     16
#define LLEN   1024
#define CINN   14
#define TSZ    256
#define HSZ    512
#define NST    32
#define ESZ    128
#define NDEPTH 6
#define QHN    (HSZ*NST)

#define RS2 0.70710678118654752f   // 1/sqrt(2)
#define IS6 0.40824829046386302f   // 1/sqrt(6)

typedef unsigned short u16;
typedef unsigned int   u32;
typedef _Float16 f16;
typedef __attribute__((ext_vector_type(2)))  _Float16 f16x2;
typedef __attribute__((ext_vector_type(4)))  _Float16 f16x4;
typedef __attribute__((ext_vector_type(8)))  _Float16 f16x8;
typedef __attribute__((ext_vector_type(16))) float    f32x16;

// workspace layout (float offsets)
#define OFF_WIP   0u          // f16 [6][4][512][8][8]  pre-swizzled ip weights
#define OFF_WOP   393216u     // f16 [6][4][512][8][8]  pre-swizzled op weights
#define OFF_LAMP  786432u     // float2 lambda^64 x 12*16384
#define OFF_WO1   1181696u    // f16 [4][256][8][8]     pre-swizzled out1 weights (x IS6)
#define OFF_BB    1214464u    // float [6][16][512]     ip_b + ip_w @ dpe
#define OFF_Y16   5388288u    // f16  [16][512][1024]
#define OFF_HT    9582592u    // f16  [16][4][1024][64] (swizzled granules)
#define OFF_GT    11679744u
#define OFF_ST    13776896u
#define OFF_ZT    15874048u   // (unused since out2 fused into gemm<2>)
#define OFF_MEAN  17971200u
#define OFF_RSTD  17987584u
#define OFF_MATS  18003968u   // f16 [12][512][3][4096]
#define WS_FLOATS 55752704u

#define MATS_PER_LAYER ((size_t)512*12288)

// direct global->LDS 16B copy (LDS dest wave-uniform base, HW adds lane*16)
__device__ __forceinline__ void gload_lds16(const void* g, void* l){
  __builtin_amdgcn_global_load_lds(
      (const __attribute__((address_space(1))) unsigned int*)g,
      (__attribute__((address_space(3))) unsigned int*)(unsigned int)(unsigned long long)l,
      16, 0, 0);
}

// swizzled granule f16-offset in a [b][kt][1024 l][8 gkL][8 f16] activation buffer.
// granule g (0..31) of row l stored at gkL = (g&7)^(l&7) within chunk kt=g>>3.
__device__ __forceinline__ size_t swz_idx(int b, int l, int g){
  return ((((size_t)b*4 + (g>>3))*1024 + l)*8 + ((g&7) ^ (l&7)))*8;
}

// ---------------- fused consts + build_mats: per (q,h) f16 matrices T,V,E ----------
__global__ __launch_bounds__(256) void build_kernel(const float* __restrict__ log_dt,
                                                    const float* __restrict__ logA,
                                                    const float* __restrict__ Aim,
                                                    const float* __restrict__ Cre,
                                                    const float* __restrict__ Cim,
                                                    const float* __restrict__ Dd,
                                                    float2* __restrict__ lamP,
                                                    f16* __restrict__ mats){
  __shared__ float Pre[65][33];
  __shared__ float Pim[65][33];
  __shared__ float Kk[64];
  __shared__ float Kpart[4][64];
  __shared__ float2 Lm[32];
  __shared__ float2 Cc[32];
  int bid = blockIdx.x;
  int q   = bid >> 9;            // 0..11
  int h   = bid & 511;
  int tid = threadIdx.x;
  if (tid < 32){
    int n = tid;
    int gid = q*QHN + h*NST + n;
    float dt  = expf(log_dt[q*HSZ + h]);
    float are = -expf(logA[gid]);
    float aim = Aim[gid];
    float dre = are*dt, dim = aim*dt;
    float e   = expf(dre);
    float lre = e*cosf(dim), lim = e*sinf(dim);
    float nre = lre - 1.f, nim = lim;
    float invden = 1.f/(are*are + aim*aim);
    float tre = (nre*are + nim*aim)*invden;
    float tim = (nim*are - nre*aim)*invden;
    float cr = Cre[gid], ci = Cim[gid];
    Lm[n] = make_float2(lre, lim);
    Cc[n] = make_float2(2.f*(cr*tre - ci*tim), 2.f*(cr*tim + ci*tre));
    float pr = lre, pi = lim;
#pragma unroll
    for (int i=0;i<6;i++){ float t2 = pr*pr - pi*pi; pi = 2.f*pr*pi; pr = t2; }
    lamP[gid] = make_float2(pr, pi);
  }
  __syncthreads();
  int n  = tid & 31;
  int pg = tid >> 5;             // 0..7
  {
    float2 l = Lm[n];
    float ar=l.x, ai=l.y;
#pragma unroll
    for (int i=0;i<3;i++){ float t2 = ar*ar - ai*ai; ai = 2.f*ar*ai; ar = t2; }
    float br=1.f, bi=0.f;
    for (int i=0;i<pg;i++){ float t2 = br*ar - bi*ai; bi = br*ai + bi*ar; br = t2; }
    float pr=br, pi=bi;
#pragma unroll
    for (int i=0;i<8;i++){
      Pre[8*pg+i][n] = pr; Pim[8*pg+i][n] = pi;
      float t2 = pr*l.x - pi*l.y; pi = pr*l.y + pi*l.x; pr = t2;
    }
    if (pg == 7){ Pre[64][n] = pr; Pim[64][n] = pi; }
  }
  __syncthreads();
  {
    int m = tid & 63, p2 = tid >> 6;
    float s = 0.f;
#pragma unroll
    for (int n2=p2*8; n2<p2*8+8; n2++){
      float2 c_ = Cc[n2];
      s += c_.x*Pre[m][n2] - c_.y*Pim[m][n2];
    }
    Kpart[p2][m] = s;
  }
  __syncthreads();
  if (tid < 64) Kk[tid] = Kpart[0][tid]+Kpart[1][tid]+Kpart[2][tid]+Kpart[3][tid];
  __syncthreads();
  float Kdiag = Kk[0] + Dd[q*HSZ + h];
  f16* base = mats + (size_t)bid*12288;
#pragma unroll
  for (int jj=0; jj<6; jj++){
    int job = jj*256 + tid;       // 0..1535
    int mat = job >> 9;           // 0:T 1:V 2:E
    int rem = job & 511;
    int m = rem & 63;
    int g = rem >> 6;
    f16x8 vals;
    if (mat == 0){
#pragma unroll
      for (int j8=0;j8<8;j8++){
        int k = g*8 + j8;
        float v = (m > k) ? Kk[m-k] : ((m == k) ? Kdiag : 0.f);
        vals[j8] = (f16)v;
      }
    } else if (mat == 1){
      int n2 = m >> 1; int im = m & 1;
#pragma unroll
      for (int j8=0;j8<8;j8++){
        int k = g*8 + j8; int p = 63 - k;
        vals[j8] = (f16)(im ? Pim[p][n2] : Pre[p][n2]);
      }
    } else {
#pragma unroll
      for (int j8=0;j8<8;j8++){
        int k = g*8 + j8; int n2 = k >> 1;
        float2 c_ = Cc[n2];
        float pr = Pre[m+1][n2], pi = Pim[m+1][n2];
        float re  = c_.x*pr - c_.y*pi;
        float imv = c_.x*pi + c_.y*pr;
        vals[j8] = (f16)((k & 1) ? -imv : re);
      }
    }
    *(f16x8*)(base + mat*4096 + (g*64 + m)*8) = vals;
  }
}

// ---------------- prep2: embdpe (96, head) + inproj (256) + weight convert (800) ----
__global__ __launch_bounds__(256) void prep2(const float* __restrict__ t,  const float* __restrict__ gw,
                                             const float* __restrict__ w1, const float* __restrict__ b1,
                                             const float* __restrict__ w2, const float* __restrict__ b2,
                                             const float* __restrict__ dw, const float* __restrict__ db,
                                             const float* __restrict__ ipb, float* __restrict__ bbp,
                                             const float* __restrict__ x,  const float* __restrict__ inw,
                                             const float* __restrict__ inb,
                                             const float* __restrict__ ipw, const float* __restrict__ opw,
                                             const float* __restrict__ o1w,
                                             f16* __restrict__ WfIP, f16* __restrict__ WfOP,
                                             f16* __restrict__ WfO1, f16* __restrict__ hT){
  __shared__ __align__(16) char SMEM[49152];
  int bid = blockIdx.x;
  int tid = threadIdx.x;
  if (bid < 96){
    float* e0  = (float*)SMEM;
    float* e1  = (float*)(SMEM + 512);
    float* e2  = (float*)(SMEM + 1024);
    float* dpe = (float*)(SMEM + 1536);
    int d = bid >> 4, b = bid & 15;
    float tb = t[b];
    if (tid < 64){
      float xp = tb * gw[tid] * 6.283185307179586f;
      e0[tid]    = sinf(xp);
      e0[tid+64] = cosf(xp);
    }
    __syncthreads();
    if (tid < 128){
      float a = b1[tid];
      const float* wr = w1 + tid*128;
      for (int i=0;i<128;i++) a = fmaf(e0[i], wr[i], a);
      e1[tid] = a / (1.f + __expf(-a));
    }
    __syncthreads();
    if (tid < 128){
      float a2 = b2[tid];
      const float* wr = w2 + tid*128;
      for (int i=0;i<128;i++) a2 = fmaf(e1[i], wr[i], a2);
      e2[tid] = a2 / (1.f + __expf(-a2));
    }
    __syncthreads();
    {
      const float* wp = dw + (size_t)(d*TSZ + tid)*ESZ;
      float a = db[d*TSZ + tid];
      for (int e=0;e<128;e++) a = fmaf(e2[e], wp[e], a);
      dpe[tid] = a;
    }
    __syncthreads();
#pragma unroll
    for (int r=0;r<2;r++){
      int m = r*256 + tid;
      const float* wp = ipw + (size_t)(d*HSZ + m)*TSZ;
      float a = ipb[d*HSZ + m];
      for (int e=0;e<256;e++) a = fmaf(dpe[e], wp[e], a);
      bbp[(size_t)(d*BB + b)*HSZ + m] = a;
    }
  } else if (bid < 352){
    int pb = bid - 96;
    float* ws  = (float*)SMEM;            // 256*14
    float* bs2 = (float*)(SMEM + 14336);  // 256
    f16*  TT   = (f16*)(SMEM + 15360);    // 64*264
#pragma unroll
    for (int c=0;c<14;c++) ws[tid*14+c] = inw[tid*14+c];
    bs2[tid] = inb[tid];
    __syncthreads();
    int b  = pb >> 4;
    int l0 = (pb & 15) * 64;
    int ll = tid & 63;
    int tq = tid >> 6;
    float xv[14];
    const float* xp = x + (size_t)(b*LLEN + l0 + ll)*CINN;
#pragma unroll
    for (int c=0;c<14;c++) xv[c] = xp[c];
    for (int tt=tq*64; tt<tq*64+64; tt++){
      float a = bs2[tt];
#pragma unroll
      for (int c=0;c<14;c++) a = fmaf(ws[tt*14+c], xv[c], a);
      TT[ll*264 + tt] = (f16)a;
    }
    __syncthreads();
#pragma unroll
    for (int i=0;i<8;i++){
      int job = i*256 + tid;        // 64 l x 32 granules
      int l2 = job >> 5, gi = job & 31;
      f16x8 hv = *(const f16x8*)(TT + l2*264 + gi*8);
      *(f16x8*)(hT + swz_idx(b, l0 + l2, gi)) = hv;
    }
  } else {
    int gid = (bid - 352)*256 + tid;
    const float* src; f16* dst; float scale = 1.f;
    if (gid < 98304){
      int d = gid >> 14, rem = gid & 16383, r = rem >> 5, g = rem & 31;
      src = ipw + ((size_t)(d*512 + r))*256 + g*8;
      dst = WfIP + (size_t)d*131072 + (((g>>3)*512 + r)*8 + ((g&7)^(r&7)))*8;
    } else if (gid < 196608){
      int g2 = gid - 98304;
      int d = g2 >> 14, rem = g2 & 16383, r = rem >> 5, g = rem & 31;
      src = opw + ((size_t)(d*512 + r))*256 + g*8;
      dst = WfOP + (size_t)d*131072 + (((g>>3)*512 + r)*8 + ((g&7)^(r&7)))*8;
    } else {
      int g3 = gid - 196608;        // 0..8191
      int r = g3 >> 5, g = g3 & 31;
      src = o1w + (size_t)r*256 + g*8;
      dst = WfO1 + (((g>>3)*256 + r)*8 + ((g&7)^(r&7)))*8;
      scale = IS6;                  // fold 1/sqrt(6) into out1 weights
    }
    float4 u0 = *(const float4*)src;
    float4 u1 = *(const float4*)(src+4);
    f16x8 hv;
    hv[0]=(f16)(u0.x*scale); hv[1]=(f16)(u0.y*scale); hv[2]=(f16)(u0.z*scale); hv[3]=(f16)(u0.w*scale);
    hv[4]=(f16)(u1.x*scale); hv[5]=(f16)(u1.y*scale); hv[6]=(f16)(u1.z*scale); hv[7]=(f16)(u1.w*scale);
    *(f16x8*)dst = hv;
  }
}

// ---------------- MFMA GEMM: 512-thread blocks (8 waves, wave tile 64x32) -----------
// MODE 0: ip  (B = hT swz; bias = bb[bz][row]; out y16 [b][512][1024])
// MODE 1: op  (B = gT swz; m<2: res RMW hT; m>=2: skip RMW sT)
// MODE 2: out1+out2 fused: z=relu(...) kept in LDS; partial w2@z atomicAdd'd into out
//         (out is memset to 0 by the harness before the verification launch).
template<int MODE>
__global__ __launch_bounds__(512) void gemm_k(const f16* __restrict__ Wf, const float* __restrict__ bias,
                                              const f16* __restrict__ XT,
                                              f16* __restrict__ Y16o,
                                              f16* __restrict__ hT16, f16* __restrict__ sT16, int first,
                                              const float* __restrict__ tvec,
                                              const float* __restrict__ w2p,
                                              const float* __restrict__ b2p,
                                              float* __restrict__ outp){
  __shared__ __align__(16) f16 sm[17408];
  f16* As = sm;
  f16* Bs = sm + 8192;
  int tid = threadIdx.x;        // 0..511
  int lane = tid & 63;
  int wv = tid >> 6;            // 0..7
  int bid = blockIdx.x;
  int mi_, g;
  if (MODE == 2){
    int r = bid & 15; mi_ = r >> 3; g = (bid >> 4)*8 + (r & 7);
  } else {
    int r = bid & 31; mi_ = r >> 3; g = (bid >> 5)*8 + (r & 7);
  }
  int bz = g >> 3;
  int n_blk = (g & 7) * 128;
  int m_blk = mi_ * 128;
  const int M = (MODE==2) ? 256 : 512;
  int wm = (wv & 1) * 64;       // 0/64
  int wn = (wv >> 1) * 32;      // 0/32/64/96
  int q = lane >> 5;

  f32x16 acc[2];
#pragma unroll
  for (int mi=0;mi<2;mi++)
#pragma unroll
    for (int r=0;r<16;r++) acc[mi][r] = 0.f;

  for (int kt=0; kt<4; kt++){
    const f16* asrc = Wf + ((size_t)kt*M + m_blk)*64 + tid*8;
    const f16* bsrc = XT + ((size_t)(bz*4 + kt)*1024 + n_blk)*64 + tid*8;
#pragma unroll
    for (int i=0;i<2;i++){
      gload_lds16(asrc + i*4096, As + (i*512 + wv*64)*8);
      gload_lds16(bsrc + i*4096, Bs + (i*512 + wv*64)*8);
    }
    __syncthreads();
#pragma unroll
    for (int ks=0; ks<4; ks++){
      int gk = ks*2 + q;
      f16x8 af[2], bf;
#pragma unroll
      for (int mi=0; mi<2; mi++){
        int m = wm + mi*32 + (lane & 31);
        af[mi] = *(const f16x8*)(As + (m*8 + (gk ^ (m&7)))*8);
      }
      {
        int n = wn + (lane & 31);
        bf = *(const f16x8*)(Bs + (n*8 + (gk ^ (n&7)))*8);
      }
#pragma unroll
      for (int mi=0; mi<2; mi++)
        acc[mi] = __builtin_amdgcn_mfma_f32_32x32x16_f16(af[mi], bf, acc[mi], 0, 0, 0);
    }
    __syncthreads();
  }

  if (MODE == 0){
#pragma unroll
    for (int mi=0;mi<2;mi++){
      int col_l = wn + (lane & 31);
#pragma unroll
      for (int r=0;r<16;r++){
        int row_l = wm + mi*32 + (r&3) + 8*(r>>2) + 4*q;
        float v = acc[mi][r] + bias[bz*HSZ + m_blk + row_l];
        sm[row_l*136 + col_l] = (f16)v;
      }
    }
    __syncthreads();
#pragma unroll
    for (int i=0;i<4;i++){
      int job = i*512 + tid;          // 128 rows x 16 col-granules
      int rr = job >> 4, c8 = job & 15;
      f16x8 hv = *(const f16x8*)(sm + rr*136 + c8*8);
      *(f16x8*)(Y16o + ((size_t)bz*HSZ + m_blk + rr)*LLEN + n_blk + c8*8) = hv;
    }
  } else if (MODE == 2){
    if constexpr (MODE == 2){
      __shared__ float w2s[14*128];
      // z = relu(acc + b1) kept in LDS as sm[l*136 + m] (f16, 128 l x 128 m)
#pragma unroll
      for (int mi=0;mi<2;mi++){
        int col_l = wn + (lane & 31);
#pragma unroll
        for (int r=0;r<16;r++){
          int row_l = wm + mi*32 + (r&3) + 8*(r>>2) + 4*q;
          float v = fmaxf(acc[mi][r] + bias[m_blk + row_l], 0.f);
          sm[col_l*136 + row_l] = (f16)v;
        }
      }
      // stage this block's w2 slice: [14][m_blk..m_blk+128)
      for (int idx = tid; idx < 14*128; idx += 512){
        int c = idx >> 7, m = idx & 127;
        w2s[idx] = w2p[c*TSZ + m_blk + m];
      }
      __syncthreads();
      // partial out[c][l] = sum_{m in block} w2[c][m]*z[l][m]; 4 lanes per l
      int l = tid >> 2;           // 0..127
      int gq = tid & 3;           // m-quarter
      float a14[14];
#pragma unroll
      for (int c=0;c<14;c++) a14[c] = 0.f;
      for (int k=0;k<32;k++){
        int m = gq*32 + k;
        float zv = (float)sm[l*136 + m];
#pragma unroll
        for (int c=0;c<14;c++) a14[c] = fmaf(w2s[c*128 + m], zv, a14[c]);
      }
#pragma unroll
      for (int c=0;c<14;c++){
        a14[c] += __shfl_xor(a14[c], 1);
        a14[c] += __shfl_xor(a14[c], 2);
      }
      if (gq == 0){
        float tb = tvec[bz];
        float scale = rsqrtf(1e-4f + tb*(2e-2f - 1e-4f));
        float* op = outp + ((size_t)bz*LLEN + n_blk + l)*CINN;
#pragma unroll
        for (int c=0;c<14;c++){
          float v = a14[c]*scale;
          if (mi_ == 0) v += b2p[c]*scale;     // bias added once per (b,l,c)
          atomicAdd(op + c, v);
        }
      }
    }
  } else {
    int isRes = (mi_ < 2);
    f16* dst = isRes ? hT16 : sT16;
    int gbase = isRes ? (m_blk >> 3) : ((m_blk - TSZ) >> 3);   // 0 or 16
    int doLoad = isRes || !first;
    if (doLoad){
#pragma unroll
      for (int i=0;i<4;i++){
        int job = i*512 + tid;          // 128 n x 16 m-granules
        int n = job >> 4, m8 = job & 15;
        f16x8 hv = *(const f16x8*)(dst + swz_idx(bz, n_blk + n, gbase + m8));
        *(f16x8*)(sm + n*136 + m8*8) = hv;
      }
      __syncthreads();
    }
#pragma unroll
    for (int mi=0;mi<2;mi++){
      int col_l = wn + (lane & 31);
#pragma unroll
      for (int r=0;r<16;r++){
        int row_l = wm + mi*32 + (r&3) + 8*(r>>2) + 4*q;
        float v = acc[mi][r] + bias[m_blk + row_l];
        if (isRes){
          float old = (float)sm[col_l*136 + row_l];
          sm[col_l*136 + row_l] = (f16)((old + v)*RS2);
        } else if (first){
          sm[col_l*136 + row_l] = (f16)v;
        } else {
          float old = (float)sm[col_l*136 + row_l];
          sm[col_l*136 + row_l] = (f16)(old + v);
        }
      }
    }
    __syncthreads();
#pragma unroll
    for (int i=0;i<4;i++){
      int job = i*512 + tid;
      int n = job >> 4, m8 = job & 15;
      f16x8 hv = *(const f16x8*)(sm + n*136 + m8*8);
      *(f16x8*)(dst + swz_idx(bz, n_blk + n, gbase + m8)) = hv;
    }
  }
}

// ---------------- S4D via MFMA conv: 512-thread blocks, ONE h, all 16 batches -------
// 8 waves share the 24KB T/V/E matrix set through L1.
// NO __syncthreads(): every LDS access stays inside wave w's private 32-column strip
// of Ubuf/ZSbuf -> zero cross-wave sharing; intra-wave RAW ordered by lgkmcnt.
template<int LN>
__global__ __launch_bounds__(512) void s4_mfma(const f16* __restrict__ matsq,
                                               const float2* __restrict__ lamPq,
                                               const f16* u, f16* y,
                                               const float* __restrict__ meanp,
                                               const float* __restrict__ rstdp,
                                               const float* __restrict__ gp,
                                               const float* __restrict__ btp){
  __shared__ f16 Ubuf[256*72];
  __shared__ f16 ZSbuf[256*72];

  int tid  = threadIdx.x;
  int w    = tid >> 6;              // 0..7
  int lane = tid & 63;
  int q    = lane >> 5;
  int colL = lane & 31;
  int h  = blockIdx.x;              // 0..511

  float gv = 0.f, bv = 0.f;
  if (LN){ gv = gp[h]; bv = btp[h]; }

  const f16* matT = matsq + (size_t)h*12288;
  const f16* matV = matT + 4096;
  const f16* matE = matT + 8192;

#pragma unroll
  for (int i=0;i<4;i++){
    int fidx = i*64 + lane;               // 0..255
    int row = fidx >> 7;                  // 0/1
    int l   = (fidx & 127)*8;
    int b   = 2*w + row;
    f16x8 hv = *(const f16x8*)(u + ((size_t)b*HSZ + h)*LLEN + l);
    if (LN){
      float4 m0 = *(const float4*)(meanp + b*LLEN + l);
      float4 m1 = *(const float4*)(meanp + b*LLEN + l + 4);
      float4 r0 = *(const float4*)(rstdp + b*LLEN + l);
      float4 r1 = *(const float4*)(rstdp + b*LLEN + l + 4);
      float mm[8] = {m0.x,m0.y,m0.z,m0.w,m1.x,m1.y,m1.z,m1.w};
      float rr[8] = {r0.x,r0.y,r0.z,r0.w,r1.x,r1.y,r1.z,r1.w};
#pragma unroll
      for (int e=0;e<8;e++)
        hv[e] = (f16)(((float)hv[e] - mm[e])*rr[e]*gv + bv);
    }
    int col = (2*w + row)*16 + (l >> 6);
    *(f16x8*)(Ubuf + col*72 + (l & 63)) = hv;
  }

  int strip = w*32;

  {
    f32x16 zacc[2];
#pragma unroll
    for (int mt=0;mt<2;mt++)
#pragma unroll
      for (int r=0;r<16;r++) zacc[mt][r] = 0.f;
#pragma unroll
    for (int kt=0; kt<4; kt++){
      int kg = kt*2 + q;
      f16x8 bfrag = *(const f16x8*)(Ubuf + (strip+colL)*72 + kg*8);
#pragma unroll
      for (int mt=0; mt<2; mt++){
        f16x8 afrag = *(const f16x8*)(matV + ((size_t)(kg*64 + mt*32 + colL))*8);
        zacc[mt] = __builtin_amdgcn_mfma_f32_32x32x16_f16(afrag, bfrag, zacc[mt], 0, 0, 0);
      }
    }
#pragma unroll
    for (int mt=0;mt<2;mt++)
#pragma unroll
      for (int rg=0;rg<4;rg++){
        int st0 = mt*32 + rg*8 + q*4;
        f16x4 zp;
        zp[0]=(f16)zacc[mt][rg*4+0]; zp[1]=(f16)zacc[mt][rg*4+1];
        zp[2]=(f16)zacc[mt][rg*4+2]; zp[3]=(f16)zacc[mt][rg*4+3];
        *(f16x4*)(ZSbuf + (strip+colL)*72 + st0) = zp;
      }
  }

  // ---- prefix over 16 chunks: batched loads -> register scan -> batched stores
  {
    int n  = lane & 31;
    int colb = (2*w + (lane>>5))*16;
    float2 l64 = lamPq[h*NST + n];
    f16x2 zv[16];
#pragma unroll
    for (int c=0;c<16;c++)
      zv[c] = *(f16x2*)(ZSbuf + (colb + c)*72 + 2*n);
    float Sre = 0.f, Sim = 0.f;
#pragma unroll
    for (int c=0;c<16;c++){
      float zr = (float)zv[c][0], zi = (float)zv[c][1];
      f16x2 sp_; sp_[0] = (f16)Sre; sp_[1] = (f16)Sim;
      zv[c] = sp_;
      float nr = fmaf(l64.x, Sre, fmaf(-l64.y, Sim, zr));
      float ni = fmaf(l64.x, Sim, fmaf( l64.y, Sre, zi));
      Sre = nr; Sim = ni;
    }
#pragma unroll
    for (int c=0;c<16;c++)
      *(f16x2*)(ZSbuf + (colb + c)*72 + 2*n) = zv[c];
  }

  f32x16 yacc[2];
#pragma unroll
  for (int mt=0;mt<2;mt++)
#pragma unroll
    for (int r=0;r<16;r++) yacc[mt][r] = 0.f;
#pragma unroll
  for (int kt=0; kt<4; kt++){
    int kg = kt*2 + q;
    f16x8 bu = *(const f16x8*)(Ubuf  + (strip+colL)*72 + kg*8);
    f16x8 bs = *(const f16x8*)(ZSbuf + (strip+colL)*72 + kg*8);
#pragma unroll
    for (int mt=0; mt<2; mt++){
      f16x8 aT = *(const f16x8*)(matT + ((size_t)(kg*64 + mt*32 + colL))*8);
      yacc[mt] = __builtin_amdgcn_mfma_f32_32x32x16_f16(aT, bu, yacc[mt], 0, 0, 0);
    }
#pragma unroll
    for (int mt=0; mt<2; mt++){
      f16x8 aE = *(const f16x8*)(matE + ((size_t)(kg*64 + mt*32 + colL))*8);
      yacc[mt] = __builtin_amdgcn_mfma_f32_32x32x16_f16(aE, bs, yacc[mt], 0, 0, 0);
    }
  }

#pragma unroll
  for (int mt=0;mt<2;mt++)
#pragma unroll
    for (int rg=0;rg<4;rg++){
      int j0 = mt*32 + rg*8 + q*4;
      f16x4 yv;
      yv[0]=(f16)yacc[mt][rg*4+0]; yv[1]=(f16)yacc[mt][rg*4+1];
      yv[2]=(f16)yacc[mt][rg*4+2]; yv[3]=(f16)yacc[mt][rg*4+3];
      *(f16x4*)(ZSbuf + (strip+colL)*72 + j0) = yv;
    }
#pragma unroll
  for (int i=0;i<4;i++){
    int fidx = i*64 + lane;
    int row = fidx >> 7;
    int l   = (fidx & 127)*8;
    int b   = 2*w + row;
    int col = (2*w + row)*16 + (l >> 6);
    f16x8 hv = *(const f16x8*)(ZSbuf + col*72 + (l & 63));
    *(f16x8*)(y + ((size_t)b*HSZ + h)*LLEN + l) = hv;
  }
}

// ---------------- LN stats: coalesced f16x8 reads + wave shfl reduce ----------------
__global__ __launch_bounds__(256) void ln_stats(const f16* __restrict__ in,
                                                float* __restrict__ mean, float* __restrict__ rstd){
  __shared__ float rs[4][32];
  __shared__ float rq[4][32];
  int tid = threadIdx.x;
  int lg = tid & 3;
  int hb = tid >> 2;
  int w  = tid >> 6;
  int b  = blockIdx.x >> 5;
  int l0 = (blockIdx.x & 31) << 5;
  float s8[8], q8[8];
#pragma unroll
  for (int j=0;j<8;j++){ s8[j]=0.f; q8[j]=0.f; }
  const f16* basep = in + (size_t)(b*HSZ)*LLEN + l0 + lg*8;
#pragma unroll
  for (int i=0;i<8;i++){
    int h = hb + 64*i;
    f16x8 hv = *(const f16x8*)(basep + (size_t)h*LLEN);
#pragma unroll
    for (int j=0;j<8;j++){
      float v = (float)hv[j];
      s8[j] += v; q8[j] = fmaf(v,v,q8[j]);
    }
  }
#pragma unroll
  for (int d=4; d<64; d<<=1){
#pragma unroll
    for (int j=0;j<8;j++){
      s8[j] += __shfl_xor(s8[j], (unsigned)d);
      q8[j] += __shfl_xor(q8[j], (unsigned)d);
    }
  }
  if (((tid>>2) & 15) == 0){
#pragma unroll
    for (int j=0;j<8;j++){
      rs[w][lg*8+j] = s8[j];
      rq[w][lg*8+j] = q8[j];
    }
  }
  __syncthreads();
  if (tid < 32){
    float S = rs[0][tid]+rs[1][tid]+rs[2][tid]+rs[3][tid];
    float Q = rq[0][tid]+rq[1][tid]+rq[2][tid]+rq[3][tid];
    float mn = S * (1.f/HSZ);
    float var = Q * (1.f/HSZ) - mn*mn;
    mean[b*LLEN + l0 + tid] = mn;
    rstd[b*LLEN + l0 + tid] = rsqrtf(var + 1e-5f);
  }
}

// ---------------- LN + gate: single global pass (pass-1 loads retained in regs) -----
__global__ __launch_bounds__(256) void ln_gate_kernel(const f16* __restrict__ in, f16* __restrict__ gT,
                                                      const float* __restrict__ g, const float* __restrict__ bt){
  __shared__ float rs[4][32];
  __shared__ float rq[4][32];
  __shared__ float mbuf[32], rbuf[32];
  __shared__ f16 gbuf[32*264];
  int tid = threadIdx.x;
  int lg = tid & 3;
  int w  = tid >> 6;
  int b  = blockIdx.x >> 5;
  int l0 = (blockIdx.x & 31) << 5;
  f16x8 keep[8];
  {
    int hb = tid >> 2;
    float s8[8], q8[8];
#pragma unroll
    for (int j=0;j<8;j++){ s8[j]=0.f; q8[j]=0.f; }
    const f16* basep = in + (size_t)(b*HSZ)*LLEN + l0 + lg*8;
#pragma unroll
    for (int i=0;i<8;i++){
      int h = hb + 64*i;
      f16x8 hv = *(const f16x8*)(basep + (size_t)h*LLEN);
      keep[i] = hv;
#pragma unroll
      for (int j=0;j<8;j++){
        float v = (float)hv[j];
        s8[j] += v; q8[j] = fmaf(v,v,q8[j]);
      }
    }
#pragma unroll
    for (int d=4; d<64; d<<=1){
#pragma unroll
      for (int j=0;j<8;j++){
        s8[j] += __shfl_xor(s8[j], (unsigned)d);
        q8[j] += __shfl_xor(q8[j], (unsigned)d);
      }
    }
    if (((tid>>2) & 15) == 0){
#pragma unroll
      for (int j=0;j<8;j++){
        rs[w][lg*8+j] = s8[j];
        rq[w][lg*8+j] = q8[j];
      }
    }
  }
  __syncthreads();
  if (tid < 32){
    float S = rs[0][tid]+rs[1][tid]+rs[2][tid]+rs[3][tid];
    float Q = rq[0][tid]+rq[1][tid]+rq[2][tid]+rq[3][tid];
    float mn = S * (1.f/HSZ);
    float var = Q * (1.f/HSZ) - mn*mn;
    mbuf[tid] = mn;
    rbuf[tid] = rsqrtf(var + 1e-5f);
  }
  __syncthreads();
  {
    int tq = tid >> 2;
    float mloc[8], rloc[8];
#pragma unroll
    for (int j=0;j<8;j++){ mloc[j]=mbuf[lg*8+j]; rloc[j]=rbuf[lg*8+j]; }
#pragma unroll
    for (int i=0;i<4;i++){
      int t = tq + 64*i;
      f16x8 av = keep[i];
      f16x8 fv = keep[i+4];
      float ga = g[t], ba = bt[t], gf = g[t+256], bf2 = bt[t+256];
#pragma unroll
      for (int j=0;j<8;j++){
        float a = ((float)av[j] - mloc[j])*rloc[j]*ga + ba;
        float f = ((float)fv[j] - mloc[j])*rloc[j]*gf + bf2;
        float sg = 1.f/(1.f+__expf(-a));
        float th = 1.f - 2.f/(__expf(2.f*f)+1.f);
        gbuf[(lg*8+j)*264 + t] = (f16)(sg*th);
      }
    }
  }
  __syncthreads();
#pragma unroll
  for (int i=0;i<4;i++){
    int job = i*256 + tid;        // 32 l x 32 granules
    int ll = job >> 5, gi = job & 31;
    f16x8 hv = *(const f16x8*)(gbuf + ll*264 + gi*8);
    *(f16x8*)(gT + swz_idx(b, l0 + ll, gi)) = hv;
  }
}

// ---------------- host launcher ----------------
extern "C" void kernel_launch(void* const* d_in, const int* in_sizes, int n_in,
                              void* d_out, int out_size, void* d_ws, size_t ws_size,
                              hipStream_t stream) {
  (void)in_sizes; (void)n_in; (void)out_size;
  if (ws_size < (size_t)WS_FLOATS * 4) return;

  const float* x      = (const float*)d_in[0];
  const float* t      = (const float*)d_in[1];
  const float* gfpW   = (const float*)d_in[2];
  const float* ew1    = (const float*)d_in[3];
  const float* eb1    = (const float*)d_in[4];
  const float* ew2    = (const float*)d_in[5];
  const float* eb2    = (const float*)d_in[6];
  const float* in_w   = (const float*)d_in[7];
  const float* in_b   = (const float*)d_in[8];
  const float* out1_w = (const float*)d_in[9];
  const float* out1_b = (const float*)d_in[10];
  const float* out2_w = (const float*)d_in[11];
  const float* out2_b = (const float*)d_in[12];
  const float* dp_w   = (const float*)d_in[13];
  const float* dp_b   = (const float*)d_in[14];
  const float* ip_w   = (const float*)d_in[15];
  const float* ip_b   = (const float*)d_in[16];
  const float* op_w   = (const float*)d_in[17];
  const float* op_b   = (const float*)d_in[18];
  const float* log_dt = (const float*)d_in[19];
  const float* logA   = (const float*)d_in[20];
  const float* Aim    = (const float*)d_in[21];
  const float* Cre    = (const float*)d_in[22];
  const float* Cim    = (const float*)d_in[23];
  const float* s4D    = (const float*)d_in[24];
  const float* ln_g   = (const float*)d_in[25];
  const float* ln_b   = (const float*)d_in[26];
  float* out = (float*)d_out;
  float* ws = (float*)d_ws;

  f16*    WfIP = (f16*)(ws + OFF_WIP);
  f16*    WfOP = (f16*)(ws + OFF_WOP);
  float2* lamP = (float2*)(ws + OFF_LAMP);
  f16*    WfO1 = (f16*)(ws + OFF_WO1);
  float*  bbp  = ws + OFF_BB;
  f16*    y16  = (f16*)(ws + OFF_Y16);
  f16*    hT16 = (f16*)(ws + OFF_HT);
  f16*    gT16 = (f16*)(ws + OFF_GT);
  f16*    sT16 = (f16*)(ws + OFF_ST);
  float*  meanb = ws + OFF_MEAN;
  float*  rstdb = ws + OFF_RSTD;
  f16*    mats = (f16*)(ws + OFF_MATS);

  build_kernel<<<6144,256,0,stream>>>(log_dt, logA, Aim, Cre, Cim, s4D, lamP, mats);
  prep2<<<1152,256,0,stream>>>(t, gfpW, ew1, eb1, ew2, eb2, dp_w, dp_b, ip_b, bbp,
                               x, in_w, in_b, ip_w, op_w, out1_w,
                               WfIP, WfOP, WfO1, hT16);

  for (int d=0; d<NDEPTH; d++){
    int q0 = d*2, q1 = d*2+1;
    gemm_k<0><<<512,512,0,stream>>>(WfIP + (size_t)d*131072, bbp + (size_t)d*BB*HSZ,
                                    hT16, y16, nullptr, nullptr, 0,
                                    nullptr, nullptr, nullptr, nullptr);
    s4_mfma<0><<<512,512,0,stream>>>(mats + (size_t)q0*MATS_PER_LAYER, lamP + (size_t)q0*QHN,
                                     y16, y16, nullptr, nullptr, nullptr, nullptr);
    ln_stats<<<512,256,0,stream>>>(y16, meanb, rstdb);
    s4_mfma<1><<<512,512,0,stream>>>(mats + (size_t)q1*MATS_PER_LAYER, lamP + (size_t)q1*QHN,
                                     y16, y16, meanb, rstdb, ln_g + q0*HSZ, ln_b + q0*HSZ);
    ln_gate_kernel<<<512,256,0,stream>>>(y16, gT16, ln_g + q1*HSZ, ln_b + q1*HSZ);
    gemm_k<1><<<512,512,0,stream>>>(WfOP + (size_t)d*131072, op_b + d*HSZ,
                                    gT16, nullptr, hT16, sT16, (d==0)?1:0,
                                    nullptr, nullptr, nullptr, nullptr);
  }
  // out1+out2 fused: relu'd z stays in LDS; partial w2@z atomically accumulated into out
  gemm_k<2><<<256,512,0,stream>>>(WfO1, out1_b, sT16, nullptr, nullptr, nullptr, 0,
                                  t, out2_w, out2_b, out);
}

// Round 14
// 598.837 us; speedup vs baseline: 1.0228x; 1.0228x over previous
//
#include <hip/hip_runtime.h>

// ---------------- problem constants ----------------
#define BB     16
#define LLEN   1024
#define CINN   14
#define TSZ    256
#define HSZ    512
#define NST    32
#define ESZ    128
#define NDEPTH 6
#define QHN    (HSZ*NST)

#define RS2 0.70710678118654752f   // 1/sqrt(2)
#define IS6 0.40824829046386302f   // 1/sqrt(6)

typedef unsigned short u16;
typedef unsigned int   u32;
typedef _Float16 f16;
typedef __attribute__((ext_vector_type(2)))  _Float16 f16x2;
typedef __attribute__((ext_vector_type(4)))  _Float16 f16x4;
typedef __attribute__((ext_vector_type(8)))  _Float16 f16x8;
typedef __attribute__((ext_vector_type(16))) float    f32x16;

// workspace layout (float offsets)
#define OFF_WIP   0u          // f16 [6][4][512][8][8]  pre-swizzled ip weights
#define OFF_WOP   393216u     // f16 [6][4][512][8][8]  pre-swizzled op weights
#define OFF_LAMP  786432u     // float2 lambda^64 x 12*16384
#define OFF_WO1   1181696u    // f16 [4][256][8][8]     pre-swizzled out1 weights (x IS6)
#define OFF_BB    1214464u    // float [6][16][512]     ip_b + ip_w @ dpe
#define OFF_Y16   5388288u    // f16  [16][512][1024]
#define OFF_HT    9582592u    // f16  [16][4][1024][64] (swizzled granules)
#define OFF_GT    11679744u
#define OFF_ST    13776896u
#define OFF_ZT    15874048u   // f16  [16][1024][256] (out1 output, linear)
#define OFF_MEAN  17971200u
#define OFF_RSTD  17987584u
#define OFF_MATS  18003968u   // f16 [12][512][3][4096]
#define WS_FLOATS 55752704u

#define MATS_PER_LAYER ((size_t)512*12288)

// direct global->LDS 16B copy (LDS dest wave-uniform base, HW adds lane*16)
__device__ __forceinline__ void gload_lds16(const void* g, void* l){
  __builtin_amdgcn_global_load_lds(
      (const __attribute__((address_space(1))) unsigned int*)g,
      (__attribute__((address_space(3))) unsigned int*)(unsigned int)(unsigned long long)l,
      16, 0, 0);
}

// swizzled granule f16-offset in a [b][kt][1024 l][8 gkL][8 f16] activation buffer.
// granule g (0..31) of row l stored at gkL = (g&7)^(l&7) within chunk kt=g>>3.
__device__ __forceinline__ size_t swz_idx(int b, int l, int g){
  return ((((size_t)b*4 + (g>>3))*1024 + l)*8 + ((g&7) ^ (l&7)))*8;
}

// ---------------- fused consts + build_mats: per (q,h) f16 matrices T,V,E ----------
// Separate kernel (19KB LDS -> 8 blocks/CU) — fusing into a 48KB-LDS kernel cut
// its write BW 3.7->2.3 TB/s (round-8 counters).
__global__ __launch_bounds__(256) void build_kernel(const float* __restrict__ log_dt,
                                                    const float* __restrict__ logA,
                                                    const float* __restrict__ Aim,
                                                    const float* __restrict__ Cre,
                                                    const float* __restrict__ Cim,
                                                    const float* __restrict__ Dd,
                                                    float2* __restrict__ lamP,
                                                    f16* __restrict__ mats){
  __shared__ float Pre[65][33];
  __shared__ float Pim[65][33];
  __shared__ float Kk[64];
  __shared__ float Kpart[4][64];
  __shared__ float2 Lm[32];
  __shared__ float2 Cc[32];
  int bid = blockIdx.x;
  int q   = bid >> 9;            // 0..11
  int h   = bid & 511;
  int tid = threadIdx.x;
  if (tid < 32){
    int n = tid;
    int gid = q*QHN + h*NST + n;
    float dt  = expf(log_dt[q*HSZ + h]);
    float are = -expf(logA[gid]);
    float aim = Aim[gid];
    float dre = are*dt, dim = aim*dt;
    float e   = expf(dre);
    float lre = e*cosf(dim), lim = e*sinf(dim);
    float nre = lre - 1.f, nim = lim;
    float invden = 1.f/(are*are + aim*aim);
    float tre = (nre*are + nim*aim)*invden;
    float tim = (nim*are - nre*aim)*invden;
    float cr = Cre[gid], ci = Cim[gid];
    Lm[n] = make_float2(lre, lim);
    Cc[n] = make_float2(2.f*(cr*tre - ci*tim), 2.f*(cr*tim + ci*tre));
    float pr = lre, pi = lim;
#pragma unroll
    for (int i=0;i<6;i++){ float t2 = pr*pr - pi*pi; pi = 2.f*pr*pi; pr = t2; }
    lamP[gid] = make_float2(pr, pi);
  }
  __syncthreads();
  int n  = tid & 31;
  int pg = tid >> 5;             // 0..7
  {
    float2 l = Lm[n];
    float ar=l.x, ai=l.y;
#pragma unroll
    for (int i=0;i<3;i++){ float t2 = ar*ar - ai*ai; ai = 2.f*ar*ai; ar = t2; }
    float br=1.f, bi=0.f;
    for (int i=0;i<pg;i++){ float t2 = br*ar - bi*ai; bi = br*ai + bi*ar; br = t2; }
    float pr=br, pi=bi;
#pragma unroll
    for (int i=0;i<8;i++){
      Pre[8*pg+i][n] = pr; Pim[8*pg+i][n] = pi;
      float t2 = pr*l.x - pi*l.y; pi = pr*l.y + pi*l.x; pr = t2;
    }
    if (pg == 7){ Pre[64][n] = pr; Pim[64][n] = pi; }
  }
  __syncthreads();
  {
    int m = tid & 63, p2 = tid >> 6;
    float s = 0.f;
#pragma unroll
    for (int n2=p2*8; n2<p2*8+8; n2++){
      float2 c_ = Cc[n2];
      s += c_.x*Pre[m][n2] - c_.y*Pim[m][n2];
    }
    Kpart[p2][m] = s;
  }
  __syncthreads();
  if (tid < 64) Kk[tid] = Kpart[0][tid]+Kpart[1][tid]+Kpart[2][tid]+Kpart[3][tid];
  __syncthreads();
  float Kdiag = Kk[0] + Dd[q*HSZ + h];
  f16* base = mats + (size_t)bid*12288;
#pragma unroll
  for (int jj=0; jj<6; jj++){
    int job = jj*256 + tid;       // 0..1535
    int mat = job >> 9;           // 0:T 1:V 2:E
    int rem = job & 511;
    int m = rem & 63;
    int g = rem >> 6;
    f16x8 vals;
    if (mat == 0){
#pragma unroll
      for (int j8=0;j8<8;j8++){
        int k = g*8 + j8;
        float v = (m > k) ? Kk[m-k] : ((m == k) ? Kdiag : 0.f);
        vals[j8] = (f16)v;
      }
    } else if (mat == 1){
      int n2 = m >> 1; int im = m & 1;
#pragma unroll
      for (int j8=0;j8<8;j8++){
        int k = g*8 + j8; int p = 63 - k;
        vals[j8] = (f16)(im ? Pim[p][n2] : Pre[p][n2]);
      }
    } else {
#pragma unroll
      for (int j8=0;j8<8;j8++){
        int k = g*8 + j8; int n2 = k >> 1;
        float2 c_ = Cc[n2];
        float pr = Pre[m+1][n2], pi = Pim[m+1][n2];
        float re  = c_.x*pr - c_.y*pi;
        float imv = c_.x*pi + c_.y*pr;
        vals[j8] = (f16)((k & 1) ? -imv : re);
      }
    }
    *(f16x8*)(base + mat*4096 + (g*64 + m)*8) = vals;
  }
}

// ---------------- prep2: embdpe (96, head) + inproj (256) + weight convert (800) ----
__global__ __launch_bounds__(256) void prep2(const float* __restrict__ t,  const float* __restrict__ gw,
                                             const float* __restrict__ w1, const float* __restrict__ b1,
                                             const float* __restrict__ w2, const float* __restrict__ b2,
                                             const float* __restrict__ dw, const float* __restrict__ db,
                                             const float* __restrict__ ipb, float* __restrict__ bbp,
                                             const float* __restrict__ x,  const float* __restrict__ inw,
                                             const float* __restrict__ inb,
                                             const float* __restrict__ ipw, const float* __restrict__ opw,
                                             const float* __restrict__ o1w,
                                             f16* __restrict__ WfIP, f16* __restrict__ WfOP,
                                             f16* __restrict__ WfO1, f16* __restrict__ hT){
  __shared__ __align__(16) char SMEM[49152];
  int bid = blockIdx.x;
  int tid = threadIdx.x;
  if (bid < 96){
    float* e0  = (float*)SMEM;
    float* e1  = (float*)(SMEM + 512);
    float* e2  = (float*)(SMEM + 1024);
    float* dpe = (float*)(SMEM + 1536);
    int d = bid >> 4, b = bid & 15;
    float tb = t[b];
    if (tid < 64){
      float xp = tb * gw[tid] * 6.283185307179586f;
      e0[tid]    = sinf(xp);
      e0[tid+64] = cosf(xp);
    }
    __syncthreads();
    if (tid < 128){
      float a = b1[tid];
      const float* wr = w1 + tid*128;
      for (int i=0;i<128;i++) a = fmaf(e0[i], wr[i], a);
      e1[tid] = a / (1.f + __expf(-a));
    }
    __syncthreads();
    if (tid < 128){
      float a2 = b2[tid];
      const float* wr = w2 + tid*128;
      for (int i=0;i<128;i++) a2 = fmaf(e1[i], wr[i], a2);
      e2[tid] = a2 / (1.f + __expf(-a2));
    }
    __syncthreads();
    {
      const float* wp = dw + (size_t)(d*TSZ + tid)*ESZ;
      float a = db[d*TSZ + tid];
      for (int e=0;e<128;e++) a = fmaf(e2[e], wp[e], a);
      dpe[tid] = a;
    }
    __syncthreads();
#pragma unroll
    for (int r=0;r<2;r++){
      int m = r*256 + tid;
      const float* wp = ipw + (size_t)(d*HSZ + m)*TSZ;
      float a = ipb[d*HSZ + m];
      for (int e=0;e<256;e++) a = fmaf(dpe[e], wp[e], a);
      bbp[(size_t)(d*BB + b)*HSZ + m] = a;
    }
  } else if (bid < 352){
    int pb = bid - 96;
    float* ws  = (float*)SMEM;            // 256*14
    float* bs2 = (float*)(SMEM + 14336);  // 256
    f16*  TT   = (f16*)(SMEM + 15360);    // 64*264
#pragma unroll
    for (int c=0;c<14;c++) ws[tid*14+c] = inw[tid*14+c];
    bs2[tid] = inb[tid];
    __syncthreads();
    int b  = pb >> 4;
    int l0 = (pb & 15) * 64;
    int ll = tid & 63;
    int tq = tid >> 6;
    float xv[14];
    const float* xp = x + (size_t)(b*LLEN + l0 + ll)*CINN;
#pragma unroll
    for (int c=0;c<14;c++) xv[c] = xp[c];
    for (int tt=tq*64; tt<tq*64+64; tt++){
      float a = bs2[tt];
#pragma unroll
      for (int c=0;c<14;c++) a = fmaf(ws[tt*14+c], xv[c], a);
      TT[ll*264 + tt] = (f16)a;
    }
    __syncthreads();
#pragma unroll
    for (int i=0;i<8;i++){
      int job = i*256 + tid;        // 64 l x 32 granules
      int l2 = job >> 5, gi = job & 31;
      f16x8 hv = *(const f16x8*)(TT + l2*264 + gi*8);
      *(f16x8*)(hT + swz_idx(b, l0 + l2, gi)) = hv;
    }
  } else {
    int gid = (bid - 352)*256 + tid;
    const float* src; f16* dst; float scale = 1.f;
    if (gid < 98304){
      int d = gid >> 14, rem = gid & 16383, r = rem >> 5, g = rem & 31;
      src = ipw + ((size_t)(d*512 + r))*256 + g*8;
      dst = WfIP + (size_t)d*131072 + (((g>>3)*512 + r)*8 + ((g&7)^(r&7)))*8;
    } else if (gid < 196608){
      int g2 = gid - 98304;
      int d = g2 >> 14, rem = g2 & 16383, r = rem >> 5, g = rem & 31;
      src = opw + ((size_t)(d*512 + r))*256 + g*8;
      dst = WfOP + (size_t)d*131072 + (((g>>3)*512 + r)*8 + ((g&7)^(r&7)))*8;
    } else {
      int g3 = gid - 196608;        // 0..8191
      int r = g3 >> 5, g = g3 & 31;
      src = o1w + (size_t)r*256 + g*8;
      dst = WfO1 + (((g>>3)*256 + r)*8 + ((g&7)^(r&7)))*8;
      scale = IS6;                  // fold 1/sqrt(6) into out1 weights
    }
    float4 u0 = *(const float4*)src;
    float4 u1 = *(const float4*)(src+4);
    f16x8 hv;
    hv[0]=(f16)(u0.x*scale); hv[1]=(f16)(u0.y*scale); hv[2]=(f16)(u0.z*scale); hv[3]=(f16)(u0.w*scale);
    hv[4]=(f16)(u1.x*scale); hv[5]=(f16)(u1.y*scale); hv[6]=(f16)(u1.z*scale); hv[7]=(f16)(u1.w*scale);
    *(f16x8*)dst = hv;
  }
}

// ---------------- MFMA GEMM: 512-thread blocks (8 waves, wave tile 64x32) -----------
// MODE 0: ip  (B = hT swz; bias = bb[bz][row]; out y16 [b][512][1024])
// MODE 1: op  (B = gT swz; m<2: res RMW hT; m>=2: skip RMW sT)
// MODE 2: out1 (B = sT swz, weights pre-scaled by IS6; relu; out zT linear)
template<int MODE>
__global__ __launch_bounds__(512) void gemm_k(const f16* __restrict__ Wf, const float* __restrict__ bias,
                                              const f16* __restrict__ XT,
                                              f16* __restrict__ Y16o,
                                              f16* __restrict__ hT16, f16* __restrict__ sT16, int first){
  __shared__ __align__(16) f16 sm[17408];
  f16* As = sm;
  f16* Bs = sm + 8192;
  int tid = threadIdx.x;        // 0..511
  int lane = tid & 63;
  int wv = tid >> 6;            // 0..7
  int bid = blockIdx.x;
  int mi_, g;
  if (MODE == 2){
    int r = bid & 15; mi_ = r >> 3; g = (bid >> 4)*8 + (r & 7);
  } else {
    int r = bid & 31; mi_ = r >> 3; g = (bid >> 5)*8 + (r & 7);
  }
  int bz = g >> 3;
  int n_blk = (g & 7) * 128;
  int m_blk = mi_ * 128;
  const int M = (MODE==2) ? 256 : 512;
  int wm = (wv & 1) * 64;       // 0/64
  int wn = (wv >> 1) * 32;      // 0/32/64/96
  int q = lane >> 5;

  f32x16 acc[2];
#pragma unroll
  for (int mi=0;mi<2;mi++)
#pragma unroll
    for (int r=0;r<16;r++) acc[mi][r] = 0.f;

  for (int kt=0; kt<4; kt++){
    const f16* asrc = Wf + ((size_t)kt*M + m_blk)*64 + tid*8;
    const f16* bsrc = XT + ((size_t)(bz*4 + kt)*1024 + n_blk)*64 + tid*8;
#pragma unroll
    for (int i=0;i<2;i++){
      gload_lds16(asrc + i*4096, As + (i*512 + wv*64)*8);
      gload_lds16(bsrc + i*4096, Bs + (i*512 + wv*64)*8);
    }
    __syncthreads();
#pragma unroll
    for (int ks=0; ks<4; ks++){
      int gk = ks*2 + q;
      f16x8 af[2], bf;
#pragma unroll
      for (int mi=0; mi<2; mi++){
        int m = wm + mi*32 + (lane & 31);
        af[mi] = *(const f16x8*)(As + (m*8 + (gk ^ (m&7)))*8);
      }
      {
        int n = wn + (lane & 31);
        bf = *(const f16x8*)(Bs + (n*8 + (gk ^ (n&7)))*8);
      }
#pragma unroll
      for (int mi=0; mi<2; mi++)
        acc[mi] = __builtin_amdgcn_mfma_f32_32x32x16_f16(af[mi], bf, acc[mi], 0, 0, 0);
    }
    __syncthreads();
  }

  if (MODE == 0){
#pragma unroll
    for (int mi=0;mi<2;mi++){
      int col_l = wn + (lane & 31);
#pragma unroll
      for (int r=0;r<16;r++){
        int row_l = wm + mi*32 + (r&3) + 8*(r>>2) + 4*q;
        float v = acc[mi][r] + bias[bz*HSZ + m_blk + row_l];
        sm[row_l*136 + col_l] = (f16)v;
      }
    }
    __syncthreads();
#pragma unroll
    for (int i=0;i<4;i++){
      int job = i*512 + tid;          // 128 rows x 16 col-granules
      int rr = job >> 4, c8 = job & 15;
      f16x8 hv = *(const f16x8*)(sm + rr*136 + c8*8);
      *(f16x8*)(Y16o + ((size_t)bz*HSZ + m_blk + rr)*LLEN + n_blk + c8*8) = hv;
    }
  } else if (MODE == 2){
#pragma unroll
    for (int mi=0;mi<2;mi++){
      int col_l = wn + (lane & 31);
#pragma unroll
      for (int r=0;r<16;r++){
        int row_l = wm + mi*32 + (r&3) + 8*(r>>2) + 4*q;
        float v = fmaxf(acc[mi][r] + bias[m_blk + row_l], 0.f);
        sm[col_l*136 + row_l] = (f16)v;
      }
    }
    __syncthreads();
#pragma unroll
    for (int i=0;i<4;i++){
      int job = i*512 + tid;
      int n = job >> 4, m8 = job & 15;
      f16x8 hv = *(const f16x8*)(sm + n*136 + m8*8);
      *(f16x8*)(Y16o + ((size_t)bz*LLEN + n_blk + n)*TSZ + m_blk + m8*8) = hv;
    }
  } else {
    int isRes = (mi_ < 2);
    f16* dst = isRes ? hT16 : sT16;
    int gbase = isRes ? (m_blk >> 3) : ((m_blk - TSZ) >> 3);   // 0 or 16
    int doLoad = isRes || !first;
    if (doLoad){
#pragma unroll
      for (int i=0;i<4;i++){
        int job = i*512 + tid;          // 128 n x 16 m-granules
        int n = job >> 4, m8 = job & 15;
        f16x8 hv = *(const f16x8*)(dst + swz_idx(bz, n_blk + n, gbase + m8));
        *(f16x8*)(sm + n*136 + m8*8) = hv;
      }
      __syncthreads();
    }
#pragma unroll
    for (int mi=0;mi<2;mi++){
      int col_l = wn + (lane & 31);
#pragma unroll
      for (int r=0;r<16;r++){
        int row_l = wm + mi*32 + (r&3) + 8*(r>>2) + 4*q;
        float v = acc[mi][r] + bias[m_blk + row_l];
        if (isRes){
          float old = (float)sm[col_l*136 + row_l];
          sm[col_l*136 + row_l] = (f16)((old + v)*RS2);
        } else if (first){
          sm[col_l*136 + row_l] = (f16)v;
        } else {
          float old = (float)sm[col_l*136 + row_l];
          sm[col_l*136 + row_l] = (f16)(old + v);
        }
      }
    }
    __syncthreads();
#pragma unroll
    for (int i=0;i<4;i++){
      int job = i*512 + tid;
      int n = job >> 4, m8 = job & 15;
      f16x8 hv = *(const f16x8*)(sm + n*136 + m8*8);
      *(f16x8*)(dst + swz_idx(bz, n_blk + n, gbase + m8)) = hv;
    }
  }
}

// ---------------- S4D via MFMA conv: 512-thread blocks, ONE h, all 16 batches -------
// 8 waves share the 24KB T/V/E matrix set through L1.
// NO __syncthreads(): every LDS access stays inside wave w's private 32-column strip
// of Ubuf/ZSbuf -> zero cross-wave sharing; intra-wave RAW ordered by lgkmcnt.
template<int LN>
__global__ __launch_bounds__(512) void s4_mfma(const f16* __restrict__ matsq,
                                               const float2* __restrict__ lamPq,
                                               const f16* u, f16* y,
                                               const float* __restrict__ meanp,
                                               const float* __restrict__ rstdp,
                                               const float* __restrict__ gp,
                                               const float* __restrict__ btp){
  __shared__ f16 Ubuf[256*72];
  __shared__ f16 ZSbuf[256*72];

  int tid  = threadIdx.x;
  int w    = tid >> 6;              // 0..7
  int lane = tid & 63;
  int q    = lane >> 5;
  int colL = lane & 31;
  int h  = blockIdx.x;              // 0..511

  float gv = 0.f, bv = 0.f;
  if (LN){ gv = gp[h]; bv = btp[h]; }

  const f16* matT = matsq + (size_t)h*12288;
  const f16* matV = matT + 4096;
  const f16* matE = matT + 8192;

#pragma unroll
  for (int i=0;i<4;i++){
    int fidx = i*64 + lane;               // 0..255
    int row = fidx >> 7;                  // 0/1
    int l   = (fidx & 127)*8;
    int b   = 2*w + row;
    f16x8 hv = *(const f16x8*)(u + ((size_t)b*HSZ + h)*LLEN + l);
    if (LN){
      float4 m0 = *(const float4*)(meanp + b*LLEN + l);
      float4 m1 = *(const float4*)(meanp + b*LLEN + l + 4);
      float4 r0 = *(const float4*)(rstdp + b*LLEN + l);
      float4 r1 = *(const float4*)(rstdp + b*LLEN + l + 4);
      float mm[8] = {m0.x,m0.y,m0.z,m0.w,m1.x,m1.y,m1.z,m1.w};
      float rr[8] = {r0.x,r0.y,r0.z,r0.w,r1.x,r1.y,r1.z,r1.w};
#pragma unroll
      for (int e=0;e<8;e++)
        hv[e] = (f16)(((float)hv[e] - mm[e])*rr[e]*gv + bv);
    }
    int col = (2*w + row)*16 + (l >> 6);
    *(f16x8*)(Ubuf + col*72 + (l & 63)) = hv;
  }

  int strip = w*32;

  {
    f32x16 zacc[2];
#pragma unroll
    for (int mt=0;mt<2;mt++)
#pragma unroll
      for (int r=0;r<16;r++) zacc[mt][r] = 0.f;
#pragma unroll
    for (int kt=0; kt<4; kt++){
      int kg = kt*2 + q;
      f16x8 bfrag = *(const f16x8*)(Ubuf + (strip+colL)*72 + kg*8);
#pragma unroll
      for (int mt=0; mt<2; mt++){
        f16x8 afrag = *(const f16x8*)(matV + ((size_t)(kg*64 + mt*32 + colL))*8);
        zacc[mt] = __builtin_amdgcn_mfma_f32_32x32x16_f16(afrag, bfrag, zacc[mt], 0, 0, 0);
      }
    }
#pragma unroll
    for (int mt=0;mt<2;mt++)
#pragma unroll
      for (int rg=0;rg<4;rg++){
        int st0 = mt*32 + rg*8 + q*4;
        f16x4 zp;
        zp[0]=(f16)zacc[mt][rg*4+0]; zp[1]=(f16)zacc[mt][rg*4+1];
        zp[2]=(f16)zacc[mt][rg*4+2]; zp[3]=(f16)zacc[mt][rg*4+3];
        *(f16x4*)(ZSbuf + (strip+colL)*72 + st0) = zp;
      }
  }

  // ---- prefix over 16 chunks: batched loads -> register scan -> batched stores
  {
    int n  = lane & 31;
    int colb = (2*w + (lane>>5))*16;
    float2 l64 = lamPq[h*NST + n];
    f16x2 zv[16];
#pragma unroll
    for (int c=0;c<16;c++)
      zv[c] = *(f16x2*)(ZSbuf + (colb + c)*72 + 2*n);
    float Sre = 0.f, Sim = 0.f;
#pragma unroll
    for (int c=0;c<16;c++){
      float zr = (float)zv[c][0], zi = (float)zv[c][1];
      f16x2 sp_; sp_[0] = (f16)Sre; sp_[1] = (f16)Sim;
      zv[c] = sp_;
      float nr = fmaf(l64.x, Sre, fmaf(-l64.y, Sim, zr));
      float ni = fmaf(l64.x, Sim, fmaf( l64.y, Sre, zi));
      Sre = nr; Sim = ni;
    }
#pragma unroll
    for (int c=0;c<16;c++)
      *(f16x2*)(ZSbuf + (colb + c)*72 + 2*n) = zv[c];
  }

  f32x16 yacc[2];
#pragma unroll
  for (int mt=0;mt<2;mt++)
#pragma unroll
    for (int r=0;r<16;r++) yacc[mt][r] = 0.f;
#pragma unroll
  for (int kt=0; kt<4; kt++){
    int kg = kt*2 + q;
    f16x8 bu = *(const f16x8*)(Ubuf  + (strip+colL)*72 + kg*8);
    f16x8 bs = *(const f16x8*)(ZSbuf + (strip+colL)*72 + kg*8);
#pragma unroll
    for (int mt=0; mt<2; mt++){
      f16x8 aT = *(const f16x8*)(matT + ((size_t)(kg*64 + mt*32 + colL))*8);
      yacc[mt] = __builtin_amdgcn_mfma_f32_32x32x16_f16(aT, bu, yacc[mt], 0, 0, 0);
    }
#pragma unroll
    for (int mt=0; mt<2; mt++){
      f16x8 aE = *(const f16x8*)(matE + ((size_t)(kg*64 + mt*32 + colL))*8);
      yacc[mt] = __builtin_amdgcn_mfma_f32_32x32x16_f16(aE, bs, yacc[mt], 0, 0, 0);
    }
  }

#pragma unroll
  for (int mt=0;mt<2;mt++)
#pragma unroll
    for (int rg=0;rg<4;rg++){
      int j0 = mt*32 + rg*8 + q*4;
      f16x4 yv;
      yv[0]=(f16)yacc[mt][rg*4+0]; yv[1]=(f16)yacc[mt][rg*4+1];
      yv[2]=(f16)yacc[mt][rg*4+2]; yv[3]=(f16)yacc[mt][rg*4+3];
      *(f16x4*)(ZSbuf + (strip+colL)*72 + j0) = yv;
    }
#pragma unroll
  for (int i=0;i<4;i++){
    int fidx = i*64 + lane;
    int row = fidx >> 7;
    int l   = (fidx & 127)*8;
    int b   = 2*w + row;
    int col = (2*w + row)*16 + (l >> 6);
    f16x8 hv = *(const f16x8*)(ZSbuf + col*72 + (l & 63));
    *(f16x8*)(y + ((size_t)b*HSZ + h)*LLEN + l) = hv;
  }
}

// ---------------- LN stats: coalesced f16x8 reads + wave shfl reduce ----------------
__global__ __launch_bounds__(256) void ln_stats(const f16* __restrict__ in,
                                                float* __restrict__ mean, float* __restrict__ rstd){
  __shared__ float rs[4][32];
  __shared__ float rq[4][32];
  int tid = threadIdx.x;
  int lg = tid & 3;
  int hb = tid >> 2;
  int w  = tid >> 6;
  int b  = blockIdx.x >> 5;
  int l0 = (blockIdx.x & 31) << 5;
  float s8[8], q8[8];
#pragma unroll
  for (int j=0;j<8;j++){ s8[j]=0.f; q8[j]=0.f; }
  const f16* basep = in + (size_t)(b*HSZ)*LLEN + l0 + lg*8;
#pragma unroll
  for (int i=0;i<8;i++){
    int h = hb + 64*i;
    f16x8 hv = *(const f16x8*)(basep + (size_t)h*LLEN);
#pragma unroll
    for (int j=0;j<8;j++){
      float v = (float)hv[j];
      s8[j] += v; q8[j] = fmaf(v,v,q8[j]);
    }
  }
#pragma unroll
  for (int d=4; d<64; d<<=1){
#pragma unroll
    for (int j=0;j<8;j++){
      s8[j] += __shfl_xor(s8[j], (unsigned)d);
      q8[j] += __shfl_xor(q8[j], (unsigned)d);
    }
  }
  if (((tid>>2) & 15) == 0){
#pragma unroll
    for (int j=0;j<8;j++){
      rs[w][lg*8+j] = s8[j];
      rq[w][lg*8+j] = q8[j];
    }
  }
  __syncthreads();
  if (tid < 32){
    float S = rs[0][tid]+rs[1][tid]+rs[2][tid]+rs[3][tid];
    float Q = rq[0][tid]+rq[1][tid]+rq[2][tid]+rq[3][tid];
    float mn = S * (1.f/HSZ);
    float var = Q * (1.f/HSZ) - mn*mn;
    mean[b*LLEN + l0 + tid] = mn;
    rstd[b*LLEN + l0 + tid] = rsqrtf(var + 1e-5f);
  }
}

// ---------------- LN + gate: single global pass (pass-1 loads retained in regs) -----
__global__ __launch_bounds__(256) void ln_gate_kernel(const f16* __restrict__ in, f16* __restrict__ gT,
                                                      const float* __restrict__ g, const float* __restrict__ bt){
  __shared__ float rs[4][32];
  __shared__ float rq[4][32];
  __shared__ float mbuf[32], rbuf[32];
  __shared__ f16 gbuf[32*264];
  int tid = threadIdx.x;
  int lg = tid & 3;
  int w  = tid >> 6;
  int b  = blockIdx.x >> 5;
  int l0 = (blockIdx.x & 31) << 5;
  f16x8 keep[8];
  {
    int hb = tid >> 2;
    float s8[8], q8[8];
#pragma unroll
    for (int j=0;j<8;j++){ s8[j]=0.f; q8[j]=0.f; }
    const f16* basep = in + (size_t)(b*HSZ)*LLEN + l0 + lg*8;
#pragma unroll
    for (int i=0;i<8;i++){
      int h = hb + 64*i;
      f16x8 hv = *(const f16x8*)(basep + (size_t)h*LLEN);
      keep[i] = hv;
#pragma unroll
      for (int j=0;j<8;j++){
        float v = (float)hv[j];
        s8[j] += v; q8[j] = fmaf(v,v,q8[j]);
      }
    }
#pragma unroll
    for (int d=4; d<64; d<<=1){
#pragma unroll
      for (int j=0;j<8;j++){
        s8[j] += __shfl_xor(s8[j], (unsigned)d);
        q8[j] += __shfl_xor(q8[j], (unsigned)d);
      }
    }
    if (((tid>>2) & 15) == 0){
#pragma unroll
      for (int j=0;j<8;j++){
        rs[w][lg*8+j] = s8[j];
        rq[w][lg*8+j] = q8[j];
      }
    }
  }
  __syncthreads();
  if (tid < 32){
    float S = rs[0][tid]+rs[1][tid]+rs[2][tid]+rs[3][tid];
    float Q = rq[0][tid]+rq[1][tid]+rq[2][tid]+rq[3][tid];
    float mn = S * (1.f/HSZ);
    float var = Q * (1.f/HSZ) - mn*mn;
    mbuf[tid] = mn;
    rbuf[tid] = rsqrtf(var + 1e-5f);
  }
  __syncthreads();
  {
    int tq = tid >> 2;
    float mloc[8], rloc[8];
#pragma unroll
    for (int j=0;j<8;j++){ mloc[j]=mbuf[lg*8+j]; rloc[j]=rbuf[lg*8+j]; }
#pragma unroll
    for (int i=0;i<4;i++){
      int t = tq + 64*i;
      f16x8 av = keep[i];
      f16x8 fv = keep[i+4];
      float ga = g[t], ba = bt[t], gf = g[t+256], bf2 = bt[t+256];
#pragma unroll
      for (int j=0;j<8;j++){
        float a = ((float)av[j] - mloc[j])*rloc[j]*ga + ba;
        float f = ((float)fv[j] - mloc[j])*rloc[j]*gf + bf2;
        float sg = 1.f/(1.f+__expf(-a));
        float th = 1.f - 2.f/(__expf(2.f*f)+1.f);
        gbuf[(lg*8+j)*264 + t] = (f16)(sg*th);
      }
    }
  }
  __syncthreads();
#pragma unroll
  for (int i=0;i<4;i++){
    int job = i*256 + tid;        // 32 l x 32 granules
    int ll = job >> 5, gi = job & 31;
    f16x8 hv = *(const f16x8*)(gbuf + ll*264 + gi*8);
    *(f16x8*)(gT + swz_idx(b, l0 + ll, gi)) = hv;
  }
}

// ---------------- out2: zT16 [b][l][256] -> out [b][l][14], coalesced ---------------
__global__ __launch_bounds__(256) void out2_kernel(const float* __restrict__ w2, const float* __restrict__ b2,
                                                   const float* __restrict__ t, const f16* __restrict__ zT,
                                                   float* __restrict__ outp){
  __shared__ f16 zt[64*264];
  __shared__ float wsm[14*256];
  __shared__ float part[64][4][16];
  __shared__ float bs[14];
  int tid = threadIdx.x;
#pragma unroll
  for (int c=0;c<14;c++) wsm[c*256+tid] = w2[c*256+tid];
  if (tid < 14) bs[tid] = b2[tid];
  int b = blockIdx.x >> 4;
  int l0 = (blockIdx.x & 15) * 64;
#pragma unroll
  for (int i=0;i<8;i++){
    int job = i*256 + tid;
    int ll = job >> 5, g8 = (job & 31)*8;
    f16x8 hv = *(const f16x8*)(zT + ((size_t)b*LLEN + l0 + ll)*TSZ + g8);
    *(f16x8*)(zt + ll*264 + g8) = hv;
  }
  __syncthreads();
  int l = tid >> 2;
  int g = tid & 3;
  float acc[14];
#pragma unroll
  for (int c=0;c<14;c++) acc[c]=0.f;
  for (int k=0;k<64;k++){
    float zv = (float)zt[l*264 + g*64 + k];
#pragma unroll
    for (int c=0;c<14;c++) acc[c] = fmaf(wsm[c*256 + g*64 + k], zv, acc[c]);
  }
#pragma unroll
  for (int c=0;c<14;c++) part[l][g][c] = acc[c];
  __syncthreads();
  if (g == 0){
    float tb = t[b];
    float scale = rsqrtf(1e-4f + tb*(2e-2f - 1e-4f));
    float* op = outp + (size_t)(b*LLEN + l0 + l)*CINN;
#pragma unroll
    for (int c=0;c<14;c++)
      op[c] = (part[l][0][c]+part[l][1][c]+part[l][2][c]+part[l][3][c] + bs[c])*scale;
  }
}

// ---------------- host launcher ----------------
extern "C" void kernel_launch(void* const* d_in, const int* in_sizes, int n_in,
                              void* d_out, int out_size, void* d_ws, size_t ws_size,
                              hipStream_t stream) {
  (void)in_sizes; (void)n_in; (void)out_size;
  if (ws_size < (size_t)WS_FLOATS * 4) return;

  const float* x      = (const float*)d_in[0];
  const float* t      = (const float*)d_in[1];
  const float* gfpW   = (const float*)d_in[2];
  const float* ew1    = (const float*)d_in[3];
  const float* eb1    = (const float*)d_in[4];
  const float* ew2    = (const float*)d_in[5];
  const float* eb2    = (const float*)d_in[6];
  const float* in_w   = (const float*)d_in[7];
  const float* in_b   = (const float*)d_in[8];
  const float* out1_w = (const float*)d_in[9];
  const float* out1_b = (const float*)d_in[10];
  const float* out2_w = (const float*)d_in[11];
  const float* out2_b = (const float*)d_in[12];
  const float* dp_w   = (const float*)d_in[13];
  const float* dp_b   = (const float*)d_in[14];
  const float* ip_w   = (const float*)d_in[15];
  const float* ip_b   = (const float*)d_in[16];
  const float* op_w   = (const float*)d_in[17];
  const float* op_b   = (const float*)d_in[18];
  const float* log_dt = (const float*)d_in[19];
  const float* logA   = (const float*)d_in[20];
  const float* Aim    = (const float*)d_in[21];
  const float* Cre    = (const float*)d_in[22];
  const float* Cim    = (const float*)d_in[23];
  const float* s4D    = (const float*)d_in[24];
  const float* ln_g   = (const float*)d_in[25];
  const float* ln_b   = (const float*)d_in[26];
  float* out = (float*)d_out;
  float* ws = (float*)d_ws;

  f16*    WfIP = (f16*)(ws + OFF_WIP);
  f16*    WfOP = (f16*)(ws + OFF_WOP);
  float2* lamP = (float2*)(ws + OFF_LAMP);
  f16*    WfO1 = (f16*)(ws + OFF_WO1);
  float*  bbp  = ws + OFF_BB;
  f16*    y16  = (f16*)(ws + OFF_Y16);
  f16*    hT16 = (f16*)(ws + OFF_HT);
  f16*    gT16 = (f16*)(ws + OFF_GT);
  f16*    sT16 = (f16*)(ws + OFF_ST);
  f16*    zT16 = (f16*)(ws + OFF_ZT);
  float*  meanb = ws + OFF_MEAN;
  float*  rstdb = ws + OFF_RSTD;
  f16*    mats = (f16*)(ws + OFF_MATS);

  build_kernel<<<6144,256,0,stream>>>(log_dt, logA, Aim, Cre, Cim, s4D, lamP, mats);
  prep2<<<1152,256,0,stream>>>(t, gfpW, ew1, eb1, ew2, eb2, dp_w, dp_b, ip_b, bbp,
                               x, in_w, in_b, ip_w, op_w, out1_w,
                               WfIP, WfOP, WfO1, hT16);

  for (int d=0; d<NDEPTH; d++){
    int q0 = d*2, q1 = d*2+1;
    gemm_k<0><<<512,512,0,stream>>>(WfIP + (size_t)d*131072, bbp + (size_t)d*BB*HSZ,
                                    hT16, y16, nullptr, nullptr, 0);
    s4_mfma<0><<<512,512,0,stream>>>(mats + (size_t)q0*MATS_PER_LAYER, lamP + (size_t)q0*QHN,
                                     y16, y16, nullptr, nullptr, nullptr, nullptr);
    ln_stats<<<512,256,0,stream>>>(y16, meanb, rstdb);
    s4_mfma<1><<<512,512,0,stream>>>(mats + (size_t)q1*MATS_PER_LAYER, lamP + (size_t)q1*QHN,
                                     y16, y16, meanb, rstdb, ln_g + q0*HSZ, ln_b + q0*HSZ);
    ln_gate_kernel<<<512,256,0,stream>>>(y16, gT16, ln_g + q1*HSZ, ln_b + q1*HSZ);
    gemm_k<1><<<512,512,0,stream>>>(WfOP + (size_t)d*131072, op_b + d*HSZ,
                                    gT16, nullptr, hT16, sT16, (d==0)?1:0);
  }
  gemm_k<2><<<256,512,0,stream>>>(WfO1, out1_b, sT16, zT16, nullptr, nullptr, 0);
  out2_kernel<<<256,256,0,stream>>>(out2_w, out2_b, t, zT16, out);
}